// Round 5
// baseline (336.175 us; speedup 1.0000x reference)
//
#include <hip/hip_runtime.h>

typedef unsigned short u16;
typedef unsigned int u32;

using f32x4  = __attribute__((ext_vector_type(4))) float;
using bf16x8 = __attribute__((ext_vector_type(8))) __bf16;

#define DEV __device__ __forceinline__

DEV u16 f2bf(float f) {                       // RTNE f32 -> bf16
  union { float f; u32 u; } x; x.f = f;
  return (u16)((x.u + 0x7fffu + ((x.u >> 16) & 1u)) >> 16);
}
DEV float bf2f(u16 h) {
  union { u32 u; float f; } x; x.u = ((u32)h) << 16;
  return x.f;
}

DEV void async_cp16(const u16* g, u16* l) {   // 16B global -> LDS direct
  __builtin_amdgcn_global_load_lds((const __attribute__((address_space(1))) void*)g,
                                   (__attribute__((address_space(3))) void*)l,
                                   16, 0, 0);
}

static constexpr int BATCH = 4096;
static constexpr int FEAT  = 512;
static constexpr int EMB   = 64;
static constexpr int HID   = 1024;
static constexpr int NC    = 64;
static constexpr int DIN   = 576;   // FEAT + EMB
static constexpr int LIB   = 256;   // LIB_X == LIB_Y == OUT_J
static constexpr int NBLK  = 512;   // grid size; co-residency guaranteed:
// __launch_bounds__(512,4) -> VGPR<=128 -> 16 waves/CU -> 2 blocks/CU x 256CU
// = 512. 3 blocks/CU impossible (24 waves x 128 VGPR > 512-reg/SIMD pool), so
// the dispatcher packs exactly 2/CU and all 512 blocks are resident.

// ---- device-scope grid barrier (counter zeroed by host memset each launch) -
DEV void gbar(int* bar) {
  __syncthreads();
  if (threadIdx.x == 0) {
    __hip_atomic_fetch_add(bar, 1, __ATOMIC_ACQ_REL, __HIP_MEMORY_SCOPE_AGENT);
    while (__hip_atomic_load(bar, __ATOMIC_ACQUIRE, __HIP_MEMORY_SCOPE_AGENT) < NBLK)
      __builtin_amdgcn_s_sleep(2);
  }
  __syncthreads();
}

// ---- cheap per-block dtype / index-width detection (1 load/thread) ---------
DEV void detect_lite(const u32* __restrict__ sraw, const u32* __restrict__ oraw,
                     int* isf32, int* ostr) {
  __shared__ int cib, conz;
  const int t = threadIdx.x;
  if (t == 0) { cib = 0; conz = 0; }
  u32 w = sraw[t];
  u32 e = (w >> 7) & 0xFFu;
  unsigned long long m1 = __ballot(e >= 100 && e <= 142);
  unsigned long long m2 = __ballot((t & 1) && oraw[t] != 0);
  __syncthreads();
  if ((t & 63) == 0) {
    atomicAdd(&cib, __popcll(m1));
    atomicAdd(&conz, __popcll(m2));
  }
  __syncthreads();
  *isf32 = (cib < (int)(blockDim.x >> 1)) ? 1 : 0;  // threshold = nthr/2
  *ostr  = (conz == 0) ? 2 : 1;               // all odd words zero -> int64
}

// ---- load 16 elems at element-offset `off`, convert to bf16 ----------------
DEV void load16_bf(u16* v, const void* __restrict__ in, size_t off, int isf32) {
  if (isf32) {
    const float4* s = (const float4*)((const float*)in + off);
    float4 a0 = s[0], a1 = s[1], a2 = s[2], a3 = s[3];
    v[0] = f2bf(a0.x); v[1] = f2bf(a0.y); v[2]  = f2bf(a0.z); v[3]  = f2bf(a0.w);
    v[4] = f2bf(a1.x); v[5] = f2bf(a1.y); v[6]  = f2bf(a1.z); v[7]  = f2bf(a1.w);
    v[8] = f2bf(a2.x); v[9] = f2bf(a2.y); v[10] = f2bf(a2.z); v[11] = f2bf(a2.w);
    v[12] = f2bf(a3.x); v[13] = f2bf(a3.y); v[14] = f2bf(a3.z); v[15] = f2bf(a3.w);
  } else {
    const uint4* s = (const uint4*)((const u16*)in + off);
    *(uint4*)&v[0] = s[0];
    *(uint4*)&v[8] = s[1];
  }
}

// ---- 64x64 transpose tile (bf16-ifying); 256-thr unit, tt = t & 255 --------
DEV void do_transpose64(u16* tile, const void* __restrict__ in,
                        u16* __restrict__ out, int R, int C,
                        int by, int bx, int isf32, int tt) {
  {
    const int r = tt >> 2, c0 = (tt & 3) * 16;
    u16 v[16];
    load16_bf(v, in, (size_t)(by * 64 + r) * C + (bx * 64 + c0), isf32);
    *(uint4*)&tile[r * 72 + c0]     = *(uint4*)&v[0];
    *(uint4*)&tile[r * 72 + c0 + 8] = *(uint4*)&v[8];
  }
  __syncthreads();
  {
    const int c = tt & 63, rs = (tt >> 6) * 16;
    u16 w[16];
#pragma unroll
    for (int i = 0; i < 16; ++i) w[i] = tile[(rs + i) * 72 + c];
    size_t oo = (size_t)(bx * 64 + c) * R + (by * 64 + rs);
    *(uint4*)&out[oo]     = *(uint4*)&w[0];
    *(uint4*)&out[oo + 8] = *(uint4*)&w[8];
  }
}

// ---- T-gemm: T[j][q] = sum_i nX[i][j] * Wx2[q][i]  (256-thr unit) ----------
DEV void tgemm_task(u16* L, const void* __restrict__ nX,
                    const void* __restrict__ Wx2, u16* __restrict__ T,
                    int mt, int nt, int isf32, int tt) {
  u16* Als = L;                   // [64 j][72]
  u16* Bls = L + 64 * 72;         // [2*64 q][32]
  const int m0 = mt * 64, q0 = nt * 64;
  const int lane = tt & 63, wid = tt >> 6;
  const int wm = wid >> 1, wn = wid & 1;
  const int lr = lane & 15, lq = lane >> 4;
  f32x4 acc[2][2] = {};
  for (int k0 = 0; k0 < LIB; k0 += 64) {
    __syncthreads();
    {
      const int r = tt >> 2, c0 = (tt & 3) * 16;
      u16 v[16];
      load16_bf(v, nX, (size_t)(k0 + r) * LIB + m0 + c0, isf32);
#pragma unroll
      for (int j = 0; j < 16; ++j) Als[(c0 + j) * 72 + r] = v[j];
      u16 w16[16];
      load16_bf(w16, Wx2, (size_t)(q0 + r) * LIB + k0 + c0, isf32);
      u16* dst = &Bls[((c0 >> 5) * 64 + r) * 32 + (c0 & 31)];
      *(uint4*)dst       = *(uint4*)&w16[0];
      *(uint4*)(dst + 8) = *(uint4*)&w16[8];
    }
    __syncthreads();
#pragma unroll
    for (int sl = 0; sl < 2; ++sl) {
      bf16x8 av[2], bv[2];
#pragma unroll
      for (int i2 = 0; i2 < 2; ++i2)
        av[i2] = *(const bf16x8*)&Als[(wm * 32 + i2 * 16 + lr) * 72 + sl * 32 + lq * 8];
#pragma unroll
      for (int j2 = 0; j2 < 2; ++j2)
        bv[j2] = *(const bf16x8*)&Bls[(sl * 64 + wn * 32 + j2 * 16 + lr) * 32 + lq * 8];
#pragma unroll
      for (int i2 = 0; i2 < 2; ++i2)
#pragma unroll
        for (int j2 = 0; j2 < 2; ++j2)
          acc[i2][j2] = __builtin_amdgcn_mfma_f32_16x16x32_bf16(av[i2], bv[j2], acc[i2][j2], 0, 0, 0);
    }
  }
#pragma unroll
  for (int j2 = 0; j2 < 2; ++j2) {
    const int gc = q0 + wn * 32 + j2 * 16 + lr;
#pragma unroll
    for (int i2 = 0; i2 < 2; ++i2) {
      const int gr = m0 + wm * 32 + i2 * 16 + lq * 4;
#pragma unroll
      for (int r = 0; r < 4; ++r)
        T[(size_t)(gr + r) * HID + gc] = f2bf(acc[i2][j2][r]);
    }
  }
}

// ---- bt-GEMM tile (round-0 proven 2-barrier loop), 256-thr unit + act flag -
// Barriers are unconditional; all work is act-guarded so inactive waves can
// participate in the block's barrier schedule.
template <int BM, int BN, int SLABS, bool RELU>
DEV void gemm_tile(u16* lds, int tt, const u16* __restrict__ A,
                   const u16* __restrict__ Bt, const void* bias, void* C,
                   int N, int K, int m0, int n0,
                   int isf32, bool cf32, bool bf32, bool act) {
  constexpr int WM = BM / 2, WN = BN / 2, TM = WM / 16, TN = WN / 16;
  u16* As = lds;                       // [SLABS][BM][32]
  u16* Bs = lds + BM * 32 * SLABS;     // [SLABS][BN][32]
  const int lane = tt & 63, wid = tt >> 6;
  const int wm = wid >> 1, wn = wid & 1;
  const int lr = lane & 15, lq = lane >> 4;
  f32x4 acc[TM][TN] = {};
  for (int k0 = 0; k0 < K; k0 += 32 * SLABS) {
    __syncthreads();
    if (act) {
#pragma unroll
      for (int sl = 0; sl < SLABS; ++sl) {
#pragma unroll
        for (int u = 0; u < BM / 64; ++u) {
          int unit = u * 256 + tt;
          int r = unit >> 2, c8 = (unit & 3) * 8;
          async_cp16(A + (size_t)(m0 + r) * K + (k0 + sl * 32 + c8),
                     &As[(sl * BM + r) * 32 + c8]);
        }
#pragma unroll
        for (int u = 0; u < BN / 64; ++u) {
          int unit = u * 256 + tt;
          int r = unit >> 2, c8 = (unit & 3) * 8;
          async_cp16(Bt + (size_t)(n0 + r) * K + (k0 + sl * 32 + c8),
                     &Bs[(sl * BN + r) * 32 + c8]);
        }
      }
    }
    __syncthreads();
    if (act) {
#pragma unroll
      for (int sl = 0; sl < SLABS; ++sl) {
        bf16x8 av[TM], bv[TN];
#pragma unroll
        for (int i = 0; i < TM; ++i)
          av[i] = *(const bf16x8*)&As[(sl * BM + wm * WM + i * 16 + lr) * 32 + lq * 8];
#pragma unroll
        for (int j = 0; j < TN; ++j)
          bv[j] = *(const bf16x8*)&Bs[(sl * BN + wn * WN + j * 16 + lr) * 32 + lq * 8];
#pragma unroll
        for (int i = 0; i < TM; ++i)
#pragma unroll
          for (int j = 0; j < TN; ++j)
            acc[i][j] = __builtin_amdgcn_mfma_f32_16x16x32_bf16(av[i], bv[j], acc[i][j], 0, 0, 0);
      }
    }
  }
  if (act) {
    // epilogue: C/D layout col=lane&15, row=(lane>>4)*4+r  [m89/m91 verified]
#pragma unroll
    for (int j = 0; j < TN; ++j) {
      const int gc = n0 + wn * WN + j * 16 + lr;
      const float bval = bias
          ? (bf32 ? ((const float*)bias)[gc] : bf2f(((const u16*)bias)[gc]))
          : 0.f;
#pragma unroll
      for (int i = 0; i < TM; ++i) {
        const int gr = m0 + wm * WM + i * 16 + lq * 4;
#pragma unroll
        for (int r = 0; r < 4; ++r) {
          float v = acc[i][j][r] + bval;
          if (RELU) v = fmaxf(v, 0.f);
          const size_t idx = (size_t)(gr + r) * N + gc;
          if (cf32) ((float*)C)[idx] = v;
          else      ((u16*)C)[idx] = f2bf(v);
        }
      }
    }
  }
}

// ---- fused persistent kernel: prep | gemm1 | gemm2 | tail ------------------
struct FArgs {
  const void *state, *emb, *Wx1, *bx1, *Wx2, *bx2, *Wy1, *by1, *Wy2, *by2, *nX, *nY;
  const int* opt;
  u16 *all_state, *h_x, *h_y, *cls_y, *WT1x, *WT1y, *WT2y, *T;
  float* b2x;
  void* out;
  int* bar;
};

static constexpr int TSTR = 266;

__global__ __launch_bounds__(512, 4) void fused_k(FArgs a) {
  // LDS union: P0 2x8704 u16 | P1 2x12288 | P2 16384 | P3 25216 -> 25216 u16
  __shared__ __align__(16) u16 lds[25216];                    // 50432 B
  __shared__ int lcnt;
  int isf32, os;
  detect_lite((const u32*)a.state, (const u32*)a.opt, &isf32, &os);
  const int bid = blockIdx.x;
  const int t = threadIdx.x;
  const int half = t >> 8, tt = t & 255;

  // ===== P0: prep — 996 256-thr units, 2/block, type-grouped (even bounds:
  // concat [0,576) | WT1x [576,720) | WT1y [720,864) | WT2y [864,928) |
  // tgemm [928,992) | b2x [992,996)) so both halves share barrier counts.
  {
    const int u = bid * 2 + half;
    u16* L = lds + half * 8704;
    if (u < 576) {                 // concat: all_state = [state | emb[opt]]
      int idx = u * 256 + tt;
      int b = idx / 36, ch = idx % 36;
      const void* base;
      size_t srcoff;
      if (ch < 32) { base = a.state; srcoff = (size_t)b * FEAT + ch * 16; }
      else {
        base = a.emb;
        srcoff = (size_t)a.opt[(size_t)b * os] * EMB + (ch - 32) * 16;
      }
      u16 o[16];
      load16_bf(o, base, srcoff, isf32);
      u16* dst = a.all_state + (size_t)b * DIN + ch * 16;
      *(uint4*)dst       = *(const uint4*)&o[0];
      *(uint4*)(dst + 8) = *(const uint4*)&o[8];
    } else if (u < 720) {
      const int v = u - 576;
      do_transpose64(L, a.Wx1, a.WT1x, DIN, HID, v >> 4, v & 15, isf32, tt);
    } else if (u < 864) {
      const int v = u - 720;
      do_transpose64(L, a.Wy1, a.WT1y, DIN, HID, v >> 4, v & 15, isf32, tt);
    } else if (u < 928) {
      const int v = u - 864;
      do_transpose64(L, a.Wy2, a.WT2y, HID, LIB, v >> 2, v & 3, isf32, tt);
    } else if (u < 992) {
      const int v = u - 928;
      tgemm_task(L, a.nX, a.Wx2, a.T, v & 3, v >> 2, isf32, tt);
    } else if (u < 996) {
      // bias': b2x[j] = sum_i bx2[i] * nX[i][j]
      float* red = (float*)L;
      const int j = (u - 992) * 64 + (tt & 63), g = tt >> 6;
      float acc = 0.f;
      for (int ii = 0; ii < 64; ++ii) {
        const int i = g * 64 + ii;
        float s = isf32 ? ((const float*)a.bx2)[i] : bf2f(((const u16*)a.bx2)[i]);
        float v = isf32 ? ((const float*)a.nX)[(size_t)i * LIB + j]
                        : bf2f(((const u16*)a.nX)[(size_t)i * LIB + j]);
        acc += s * v;
      }
      red[g * 64 + (tt & 63)] = acc;
      __syncthreads();
      if (g == 0)
        a.b2x[j] = red[tt & 63] + red[64 + (tt & 63)] +
                   red[128 + (tt & 63)] + red[192 + (tt & 63)];
    }
  }
  gbar(a.bar + 0);

  // ===== P1: gemm1 — 1024 x (128x64, BK=64) tiles, two per block (halves) ==
  {
    const int v = bid * 2 + half;
    const int x = v & 15, y = (v >> 4) & 31, z = v >> 9;
    gemm_tile<128, 64, 2, true>(lds + half * 12288, tt,
        a.all_state, z ? a.WT1y : a.WT1x, z ? a.by1 : a.bx1,
        z ? a.h_y : a.h_x, HID, DIN, y * 128, x * 64, isf32, false,
        isf32 != 0, true);
  }
  gbar(a.bar + 1);

  // ===== P2: gemm2 — 512 x (64x64, BK=128) tasks, 1/block, waves 0-3 =======
  {
    const int x = bid & 3, y = (bid >> 2) & 63, z = bid >> 8;
    const u16* A2   = z ? a.h_y : a.h_x;
    const u16* Bt2  = z ? a.WT2y : a.T;
    const void* bi2 = z ? a.by2 : (const void*)a.b2x;
    void* C2        = z ? (void*)a.cls_y : a.out;
    const bool cf2  = (!z) && isf32;          // out0 f32 iff input f32
    const bool bf2  = z ? (isf32 != 0) : true; // b2x always f32
    gemm_tile<64, 64, 4, false>(lds, tt, A2, Bt2, bi2, C2, LIB, HID,
                                y * 64, x * 64, isf32, cf2, bf2, half == 0);
  }
  gbar(a.bar + 2);

  // ===== P3: tail — routed gatherY, 512 tasks, 1/block, waves 0-3 ==========
  {
    const bool act = (half == 0);
    const bool of32 = (isf32 != 0);
    const int lane = tt & 63, w = tt >> 6, lr = lane & 15, lq = lane >> 4;
    u16* Bts  = lds;                  // [64 n][266]
    u16* Asm  = lds + 64 * TSTR;      // [16][266]
    u16* list = lds + 80 * TSTR;      // up to 2048 row ids
    const int m = bid >> 3;
    const int n0 = ((bid >> 1) & 3) * 64;
    const int bh = bid & 1;           // scan b in [bh*2048, bh*2048+2048)
    if (t == 0) lcnt = 0;

    if (act) {
#pragma unroll
      for (int pass = 0; pass < 4; ++pass) {
        const int k = pass * 64 + (tt >> 2), nc = (tt & 3) * 16;
        u16 v[16];
        load16_bf(v, a.nY, ((size_t)m * LIB + k) * LIB + n0 + nc, isf32);
#pragma unroll
        for (int j = 0; j < 16; ++j) Bts[(nc + j) * TSTR + k] = v[j];
      }
    }
    __syncthreads();                  // lcnt=0 + Bts ordering baseline
    if (act) {
      const int bstart = bh * (BATCH / 2), bend = bstart + BATCH / 2;
      for (int base = bstart; base < bend; base += 256) {
        const int b = base + tt;
        const int e = a.opt[(size_t)b * os];
        unsigned long long mk = __ballot(e == m);
        const int nw = __popcll(mk);
        int wbase = 0;
        if (lane == 0 && nw) wbase = atomicAdd(&lcnt, nw);
        wbase = __shfl(wbase, 0);
        const int mypre = __popcll(mk & ((1ull << lane) - 1ull));
        if (e == m) list[wbase + mypre] = (u16)b;
      }
    }
    __syncthreads();
    const int cnt = lcnt;
    const size_t out_off = (size_t)BATCH * LIB;

    for (int ch = 0; ch < cnt; ch += 16) {
      __syncthreads();
      if (act) {
        const int r = tt >> 4, cb = (tt & 15) * 16;
        if (ch + r < cnt) {
          const u16* src = a.cls_y + (size_t)list[ch + r] * LIB + cb;
          *(uint4*)&Asm[r * TSTR + cb]     = *(const uint4*)src;
          *(uint4*)&Asm[r * TSTR + cb + 8] = *(const uint4*)(src + 8);
        } else {
          uint4 z4{0, 0, 0, 0};
          *(uint4*)&Asm[r * TSTR + cb]     = z4;
          *(uint4*)&Asm[r * TSTR + cb + 8] = z4;
        }
      }
      __syncthreads();
      if (act) {
        f32x4 acc = {};
#pragma unroll
        for (int kk = 0; kk < LIB; kk += 32) {
          bf16x8 av = *(const bf16x8*)&Asm[lr * TSTR + kk + lq * 8];
          bf16x8 bv = *(const bf16x8*)&Bts[(w * 16 + lr) * TSTR + kk + lq * 8];
          acc = __builtin_amdgcn_mfma_f32_16x16x32_bf16(av, bv, acc, 0, 0, 0);
        }
#pragma unroll
        for (int r = 0; r < 4; ++r) {
          const int rowc = lq * 4 + r;
          if (ch + rowc < cnt) {
            const size_t oi = out_off + (size_t)list[ch + rowc] * LIB
                            + (n0 + w * 16 + lr);
            if (of32) ((float*)a.out)[oi] = acc[r];
            else      ((u16*)a.out)[oi] = f2bf(acc[r]);
          }
        }
      }
    }
  }
}

extern "C" void kernel_launch(void* const* d_in, const int* in_sizes, int n_in,
                              void* d_out, int out_size, void* d_ws, size_t ws_size,
                              hipStream_t stream) {
  char* p = (char*)d_ws;
  auto alloc = [&](size_t bytes) { char* r = p; p += (bytes + 255) & ~(size_t)255; return r; };
  int* bar = (int*)alloc(3 * sizeof(int));
  u16* all_state = (u16*)alloc((size_t)BATCH * DIN * 2);
  u16* h_x   = (u16*)alloc((size_t)BATCH * HID * 2);
  u16* h_y   = (u16*)alloc((size_t)BATCH * HID * 2);
  u16* cls_y = (u16*)alloc((size_t)BATCH * LIB * 2);
  u16* WT1x  = (u16*)alloc((size_t)HID * DIN * 2);
  u16* WT1y  = (u16*)alloc((size_t)HID * DIN * 2);
  u16* WT2y  = (u16*)alloc((size_t)LIB * HID * 2);
  u16* T     = (u16*)alloc((size_t)LIB * HID * 2);
  float* b2x = (float*)alloc((size_t)LIB * 4);

  hipMemsetAsync(bar, 0, 3 * sizeof(int), stream);   // phase counters = 0

  FArgs fa;
  fa.state = d_in[0]; fa.opt = (const int*)d_in[1]; fa.emb = d_in[2];
  fa.Wx1 = d_in[3]; fa.bx1 = d_in[4]; fa.Wx2 = d_in[5]; fa.bx2 = d_in[6];
  fa.Wy1 = d_in[7]; fa.by1 = d_in[8]; fa.Wy2 = d_in[9]; fa.by2 = d_in[10];
  fa.nX = d_in[11]; fa.nY = d_in[12];
  fa.all_state = all_state; fa.h_x = h_x; fa.h_y = h_y; fa.cls_y = cls_y;
  fa.WT1x = WT1x; fa.WT1y = WT1y; fa.WT2y = WT2y; fa.T = T; fa.b2x = b2x;
  fa.out = d_out; fa.bar = bar;

  fused_k<<<NBLK, 512, 0, stream>>>(fa);
}

// Round 6
// 163.189 us; speedup vs baseline: 2.0600x; 2.0600x over previous
//
#include <hip/hip_runtime.h>

typedef unsigned short u16;
typedef unsigned int u32;

using f32x4  = __attribute__((ext_vector_type(4))) float;
using bf16x8 = __attribute__((ext_vector_type(8))) __bf16;

#define DEV __device__ __forceinline__

DEV u16 f2bf(float f) {                       // RTNE f32 -> bf16
  union { float f; u32 u; } x; x.f = f;
  return (u16)((x.u + 0x7fffu + ((x.u >> 16) & 1u)) >> 16);
}
DEV float bf2f(u16 h) {
  union { u32 u; float f; } x; x.u = ((u32)h) << 16;
  return x.f;
}

DEV void async_cp16(const u16* g, u16* l) {   // 16B global -> LDS direct
  __builtin_amdgcn_global_load_lds((const __attribute__((address_space(1))) void*)g,
                                   (__attribute__((address_space(3))) void*)l,
                                   16, 0, 0);
}

static constexpr int BATCH = 4096;
static constexpr int FEAT  = 512;
static constexpr int EMB   = 64;
static constexpr int HID   = 1024;
static constexpr int NC    = 64;
static constexpr int DIN   = 576;   // FEAT + EMB
static constexpr int LIB   = 256;   // LIB_X == LIB_Y == OUT_J

// ---- cheap per-block dtype / index-width detection (1 load/thread) ---------
DEV void detect_lite(const u32* __restrict__ sraw, const u32* __restrict__ oraw,
                     int* isf32, int* ostr) {
  __shared__ int cib, conz;
  const int t = threadIdx.x;
  if (t == 0) { cib = 0; conz = 0; }
  u32 w = sraw[t];
  u32 e = (w >> 7) & 0xFFu;
  unsigned long long m1 = __ballot(e >= 100 && e <= 142);
  unsigned long long m2 = __ballot((t & 1) && oraw[t] != 0);
  __syncthreads();
  if ((t & 63) == 0) {
    atomicAdd(&cib, __popcll(m1));
    atomicAdd(&conz, __popcll(m2));
  }
  __syncthreads();
  *isf32 = (cib < 128) ? 1 : 0;               // low halves not bf16-like -> f32
  *ostr  = (conz == 0) ? 2 : 1;               // all odd words zero -> int64
}

// ---- load 16 elems at element-offset `off`, convert to bf16 ----------------
DEV void load16_bf(u16* v, const void* __restrict__ in, size_t off, int isf32) {
  if (isf32) {
    const float4* s = (const float4*)((const float*)in + off);
    float4 a0 = s[0], a1 = s[1], a2 = s[2], a3 = s[3];
    v[0] = f2bf(a0.x); v[1] = f2bf(a0.y); v[2]  = f2bf(a0.z); v[3]  = f2bf(a0.w);
    v[4] = f2bf(a1.x); v[5] = f2bf(a1.y); v[6]  = f2bf(a1.z); v[7]  = f2bf(a1.w);
    v[8] = f2bf(a2.x); v[9] = f2bf(a2.y); v[10] = f2bf(a2.z); v[11] = f2bf(a2.w);
    v[12] = f2bf(a3.x); v[13] = f2bf(a3.y); v[14] = f2bf(a3.z); v[15] = f2bf(a3.w);
  } else {
    const uint4* s = (const uint4*)((const u16*)in + off);
    *(uint4*)&v[0] = s[0];
    *(uint4*)&v[8] = s[1];
  }
}

// ---- 64x64 transpose tile (bf16-ifying), vectorized both directions --------
DEV void do_transpose64(u16* lds, const void* __restrict__ in,
                        u16* __restrict__ out, int R, int C,
                        int by, int bx, int isf32) {
  u16* tile = lds;                            // 64*72 u16
  const int t = threadIdx.x;
  {
    const int r = t >> 2, c0 = (t & 3) * 16;
    u16 v[16];
    load16_bf(v, in, (size_t)(by * 64 + r) * C + (bx * 64 + c0), isf32);
    *(uint4*)&tile[r * 72 + c0]     = *(uint4*)&v[0];
    *(uint4*)&tile[r * 72 + c0 + 8] = *(uint4*)&v[8];
  }
  __syncthreads();
  {
    const int c = t & 63, rs = (t >> 6) * 16;
    u16 w[16];
#pragma unroll
    for (int i = 0; i < 16; ++i) w[i] = tile[(rs + i) * 72 + c];
    size_t oo = (size_t)(bx * 64 + c) * R + (by * 64 + rs);
    *(uint4*)&out[oo]     = *(uint4*)&w[0];
    *(uint4*)&out[oo + 8] = *(uint4*)&w[8];
  }
}

// ---- T-gemm: T[j][q] = sum_i nX[i][j] * Wx2[q][i]  (bt layout for gemm2-x) -
DEV void tgemm_task(u16* lds, const void* __restrict__ nX,
                    const void* __restrict__ Wx2, u16* __restrict__ T,
                    int mt, int nt, int isf32) {
  u16* Als = lds;                 // [64 j][72]  (64 i-slab + pad)
  u16* Bls = lds + 64 * 72;       // [2*64 q][32]
  const int t = threadIdx.x;
  const int m0 = mt * 64, q0 = nt * 64;
  const int lane = t & 63, wid = t >> 6;
  const int wm = wid >> 1, wn = wid & 1;
  const int lr = lane & 15, lq = lane >> 4;
  f32x4 acc[2][2] = {};
  for (int k0 = 0; k0 < LIB; k0 += 64) {
    __syncthreads();
    {
      const int r = t >> 2, c0 = (t & 3) * 16;
      u16 v[16];
      load16_bf(v, nX, (size_t)(k0 + r) * LIB + m0 + c0, isf32);
#pragma unroll
      for (int j = 0; j < 16; ++j) Als[(c0 + j) * 72 + r] = v[j];
      const int q = t >> 2, ic = (t & 3) * 16;
      u16 w16[16];
      load16_bf(w16, Wx2, (size_t)(q0 + q) * LIB + k0 + ic, isf32);
      u16* dst = &Bls[((ic >> 5) * 64 + q) * 32 + (ic & 31)];
      *(uint4*)dst       = *(uint4*)&w16[0];
      *(uint4*)(dst + 8) = *(uint4*)&w16[8];
    }
    __syncthreads();
#pragma unroll
    for (int sl = 0; sl < 2; ++sl) {
      bf16x8 av[2], bv[2];
#pragma unroll
      for (int i2 = 0; i2 < 2; ++i2)
        av[i2] = *(const bf16x8*)&Als[(wm * 32 + i2 * 16 + lr) * 72 + sl * 32 + lq * 8];
#pragma unroll
      for (int j2 = 0; j2 < 2; ++j2)
        bv[j2] = *(const bf16x8*)&Bls[(sl * 64 + wn * 32 + j2 * 16 + lr) * 32 + lq * 8];
#pragma unroll
      for (int i2 = 0; i2 < 2; ++i2)
#pragma unroll
        for (int j2 = 0; j2 < 2; ++j2)
          acc[i2][j2] = __builtin_amdgcn_mfma_f32_16x16x32_bf16(av[i2], bv[j2], acc[i2][j2], 0, 0, 0);
    }
  }
#pragma unroll
  for (int j2 = 0; j2 < 2; ++j2) {
    const int gc = q0 + wn * 32 + j2 * 16 + lr;
#pragma unroll
    for (int i2 = 0; i2 < 2; ++i2) {
      const int gr = m0 + wm * 32 + i2 * 16 + lq * 4;
#pragma unroll
      for (int r = 0; r < 4; ++r)
        T[(size_t)(gr + r) * HID + gc] = f2bf(acc[i2][j2][r]);
    }
  }
}

// ---- prep: concat | WT1x | WT1y  (pure copies feeding gemm1; 864 blocks) ---
struct PrepArgs {
  const void *state, *emb, *Wx1, *Wy1;
  const int* opt;
  u16 *all_state, *WT1x, *WT1y;
};
static constexpr int PB_CONCAT = BATCH * 36 / 256;            // 576
static constexpr int PB_WT1 = (DIN / 64) * (HID / 64);        // 144
static constexpr int PREP_BLOCKS = PB_CONCAT + 2 * PB_WT1;    // 864

__global__ __launch_bounds__(256) void prep_k(PrepArgs a) {
  __shared__ __align__(16) u16 plds[64 * 72];                 // 9216 B
  int isf32, os;
  detect_lite((const u32*)a.state, (const u32*)a.opt, &isf32, &os);
  int bid = blockIdx.x;
  const int t = threadIdx.x;
  if (bid < PB_CONCAT) {
    int idx = bid * 256 + t;
    int b = idx / 36, ch = idx % 36;
    const void* base;
    size_t srcoff;
    if (ch < 32) { base = a.state; srcoff = (size_t)b * FEAT + ch * 16; }
    else {
      base = a.emb;
      srcoff = (size_t)a.opt[(size_t)b * os] * EMB + (ch - 32) * 16;
    }
    u16 o[16];
    load16_bf(o, base, srcoff, isf32);
    u16* dst = a.all_state + (size_t)b * DIN + ch * 16;
    *(uint4*)dst       = *(const uint4*)&o[0];
    *(uint4*)(dst + 8) = *(const uint4*)&o[8];
    return;
  }
  bid -= PB_CONCAT;
  if (bid < PB_WT1) { do_transpose64(plds, a.Wx1, a.WT1x, DIN, HID, bid >> 4, bid & 15, isf32); return; }
  bid -= PB_WT1;
  do_transpose64(plds, a.Wy1, a.WT1y, DIN, HID, bid >> 4, bid & 15, isf32);
}

// ---- bt-GEMM tile, BK=32*SLABS multi-slab, K-range [kbeg,kend) -------------
// (round-0 proven single-buffer 2-barrier structure)
template <int BM, int BN, int SLABS, bool RELU>
DEV void gemm_tile(u16* lds, const u16* __restrict__ A, const u16* __restrict__ Bt,
                   const void* bias, void* C, int N, int K, int m0, int n0,
                   int kbeg, int kend, int isf32, bool cf32, bool bf32) {
  constexpr int WM = BM / 2, WN = BN / 2, TM = WM / 16, TN = WN / 16;
  u16* As = lds;                       // [SLABS][BM][32]
  u16* Bs = lds + BM * 32 * SLABS;     // [SLABS][BN][32]
  const int t = threadIdx.x;
  const int lane = t & 63, wid = t >> 6;
  const int wm = wid >> 1, wn = wid & 1;
  const int lr = lane & 15, lq = lane >> 4;
  f32x4 acc[TM][TN] = {};
  for (int k0 = kbeg; k0 < kend; k0 += 32 * SLABS) {
    __syncthreads();
#pragma unroll
    for (int sl = 0; sl < SLABS; ++sl) {
#pragma unroll
      for (int u = 0; u < BM / 64; ++u) {
        int unit = u * 256 + t;
        int r = unit >> 2, c8 = (unit & 3) * 8;
        async_cp16(A + (size_t)(m0 + r) * K + (k0 + sl * 32 + c8),
                   &As[(sl * BM + r) * 32 + c8]);
      }
#pragma unroll
      for (int u = 0; u < BN / 64; ++u) {
        int unit = u * 256 + t;
        int r = unit >> 2, c8 = (unit & 3) * 8;
        async_cp16(Bt + (size_t)(n0 + r) * K + (k0 + sl * 32 + c8),
                   &Bs[(sl * BN + r) * 32 + c8]);
      }
    }
    __syncthreads();
#pragma unroll
    for (int sl = 0; sl < SLABS; ++sl) {
      bf16x8 av[TM], bv[TN];
#pragma unroll
      for (int i = 0; i < TM; ++i)
        av[i] = *(const bf16x8*)&As[(sl * BM + wm * WM + i * 16 + lr) * 32 + lq * 8];
#pragma unroll
      for (int j = 0; j < TN; ++j)
        bv[j] = *(const bf16x8*)&Bs[(sl * BN + wn * WN + j * 16 + lr) * 32 + lq * 8];
#pragma unroll
      for (int i = 0; i < TM; ++i)
#pragma unroll
        for (int j = 0; j < TN; ++j)
          acc[i][j] = __builtin_amdgcn_mfma_f32_16x16x32_bf16(av[i], bv[j], acc[i][j], 0, 0, 0);
    }
  }
  // epilogue: C/D layout col=lane&15, row=(lane>>4)*4+r  [m89/m91 verified]
#pragma unroll
  for (int j = 0; j < TN; ++j) {
    const int gc = n0 + wn * WN + j * 16 + lr;
    const float bval = bias
        ? (bf32 ? ((const float*)bias)[gc] : bf2f(((const u16*)bias)[gc]))
        : 0.f;
#pragma unroll
    for (int i = 0; i < TM; ++i) {
      const int gr = m0 + wm * WM + i * 16 + lq * 4;
#pragma unroll
      for (int r = 0; r < 4; ++r) {
        float v = acc[i][j][r] + bval;
        if (RELU) v = fmaxf(v, 0.f);
        const size_t idx = (size_t)(gr + r) * N + gc;
        if (cf32) ((float*)C)[idx] = v;
        else      ((u16*)C)[idx] = f2bf(v);
      }
    }
  }
}

// ---- gemm1: layer-1 both heads (1024 blocks, r12 mapping) + side-tasks:
// 1024..1087 WT2y transpose | 1088..1151 T-gemm | 1152..1155 bias'
struct G1Args {
  const u16 *all_state, *WT1x, *WT1y;
  const void *bx1, *by1, *Wy2, *nX, *Wx2, *bx2, *state, *opt;
  u16 *h_x, *h_y, *WT2y, *T;
  float* b2x;
};
static constexpr int G1_GEMM = 1024;
static constexpr int G1_BLOCKS = G1_GEMM + 64 + 64 + 4;       // 1156

__global__ __launch_bounds__(256) void gemm1_k(G1Args a) {
  __shared__ __align__(16) u16 lds[(128 + 64) * 96];          // 36864 B
  __shared__ float red[4][64];
  int isf32, os;
  detect_lite((const u32*)a.state, (const u32*)a.opt, &isf32, &os);
  int bid = blockIdx.x;
  const int t = threadIdx.x;
  if (bid < G1_GEMM) {
    const int x = bid & 15, y = (bid >> 4) & 31, z = bid >> 9;
    gemm_tile<128, 64, 3, true>(lds,
        a.all_state, z ? a.WT1y : a.WT1x, z ? a.by1 : a.bx1,
        z ? a.h_y : a.h_x, HID, DIN, y * 128, x * 64, 0, DIN,
        isf32, false, isf32 != 0);
    return;
  }
  bid -= G1_GEMM;
  if (bid < 64) { do_transpose64(lds, a.Wy2, a.WT2y, HID, LIB, bid >> 2, bid & 3, isf32); return; }
  bid -= 64;
  if (bid < 64) { tgemm_task(lds, a.nX, a.Wx2, a.T, bid & 3, bid >> 2, isf32); return; }
  bid -= 64;
  // bias': b2x[j] = sum_i bx2[i] * nX[i][j]  (4 blocks x 64 j, i-parallel x4)
  {
    const int j = bid * 64 + (t & 63), g = t >> 6;
    float acc = 0.f;
    for (int ii = 0; ii < 64; ++ii) {
      const int i = g * 64 + ii;
      float s = isf32 ? ((const float*)a.bx2)[i] : bf2f(((const u16*)a.bx2)[i]);
      float v = isf32 ? ((const float*)a.nX)[(size_t)i * LIB + j]
                      : bf2f(((const u16*)a.nX)[(size_t)i * LIB + j]);
      acc += s * v;
    }
    red[g][t & 63] = acc;
    __syncthreads();
    if (g == 0)
      a.b2x[j] = red[0][t & 63] + red[1][t & 63] + red[2][t & 63] + red[3][t & 63];
  }
}

// ---- gemm2: split-K x2 -> f32 partials. grid (4 n, 64 m, 4 = head*2+half),
// 1024 blocks = 4/CU = 16 waves/CU (2x the old 8 -> staging-latency fix).
// part layout: [head*2+half][BATCH][LIB] f32, no bias (bias added at combine).
struct G2Args {
  const u16 *h_x, *h_y, *T, *WT2y;
  float* part;
  const void *state, *opt;
};

__global__ __launch_bounds__(256) void gemm2_k(G2Args a) {
  __shared__ __align__(16) u16 lds[(64 + 64) * 32 * 4];       // 32768 B
  int isf32, os;
  detect_lite((const u32*)a.state, (const u32*)a.opt, &isf32, &os);
  const int head = blockIdx.z >> 1, half = blockIdx.z & 1;
  const u16* A  = head ? a.h_y : a.h_x;
  const u16* Bt = head ? a.WT2y : a.T;
  float* C = a.part + (size_t)blockIdx.z * BATCH * LIB;
  const int kbeg = half * (HID / 2);
  gemm_tile<64, 64, 4, false>(lds, A, Bt, nullptr, C, LIB, HID,
                              blockIdx.y * 64, blockIdx.x * 64,
                              kbeg, kbeg + HID / 2, isf32, true, true);
}

// ---- tail: routed gatherY (512 blocks) + out0 combine (256 blocks) ---------
// Gather blocks: Asm rows = bf16(py0 + py1 + by2) -- the y-head K-split
// combine fused into the existing cls_y gather (f32 adds, then one bf16 rnd).
// Combine blocks: out0 = px0 + px1 + b2x (disjoint output region, no ordering
// needed vs gather). Tail grid 768 = exactly 3 blocks/CU at 50 KB LDS.
struct TailArgs {
  const float* part;              // [4][BATCH][LIB] f32
  const void *nY, *state, *by2;
  const float* b2x;
  const int* opt;
  void* out;                      // out0 at 0, out1 at BATCH*LIB
};

static constexpr int TSTR = 266;

__global__ __launch_bounds__(256) void tail_k(TailArgs a) {
  __shared__ __align__(16) u16 lds[25216];  // Bts 64x266 | Asm 16x266 | list
  __shared__ int lcnt;
  int isf32, os;
  detect_lite((const u32*)a.state, (const u32*)a.opt, &isf32, &os);
  const bool of32 = (isf32 != 0);
  const int t = threadIdx.x;

  if (blockIdx.x >= 512) {                   // ---- out0 combine ----
    const int cb = blockIdx.x - 512;         // 256 blocks x 4096 elems
    const size_t e0 = ((size_t)cb * 256 + t) * 16;
    const float4* s0 = (const float4*)(a.part + e0);                  // x half0
    const float4* s1 = (const float4*)(a.part + (size_t)BATCH * LIB + e0);
    const int c0 = (int)(e0 & 255);
    float v[16];
#pragma unroll
    for (int q = 0; q < 4; ++q) {
      float4 x0 = s0[q], x1 = s1[q];
      v[q * 4 + 0] = x0.x + x1.x + a.b2x[c0 + q * 4 + 0];
      v[q * 4 + 1] = x0.y + x1.y + a.b2x[c0 + q * 4 + 1];
      v[q * 4 + 2] = x0.z + x1.z + a.b2x[c0 + q * 4 + 2];
      v[q * 4 + 3] = x0.w + x1.w + a.b2x[c0 + q * 4 + 3];
    }
    if (of32) {
      float4* d = (float4*)((float*)a.out + e0);
#pragma unroll
      for (int q = 0; q < 4; ++q) d[q] = make_float4(v[q*4], v[q*4+1], v[q*4+2], v[q*4+3]);
    } else {
      u16 o[16];
#pragma unroll
      for (int j = 0; j < 16; ++j) o[j] = f2bf(v[j]);
      u16* d = (u16*)a.out + e0;
      *(uint4*)d       = *(const uint4*)&o[0];
      *(uint4*)(d + 8) = *(const uint4*)&o[8];
    }
    return;
  }

  // ---- gather blocks (as round-0, cls_y materialization replaced by
  // on-the-fly y-partial combine) ----
  const int lane = t & 63, w = t >> 6, lr = lane & 15, lq = lane >> 4;
  u16* Bts  = lds;                    // [64 n][266]  B[n][k] = nY[m][k][n0+n]
  u16* Asm  = lds + 64 * TSTR;        // [16][266]
  u16* list = lds + 80 * TSTR;        // up to 2048 row ids
  const int m = blockIdx.x >> 3;
  const int n0 = ((blockIdx.x >> 1) & 3) * 64;
  const int half = blockIdx.x & 1;    // scan b in [half*2048, half*2048+2048)
  if (t == 0) lcnt = 0;

  const float* py0 = a.part + (size_t)2 * BATCH * LIB;   // y half0
  const float* py1 = a.part + (size_t)3 * BATCH * LIB;   // y half1
  float byv[16];                       // per-thread by2 slice (col cb..cb+15)
  {
    const int cb = (t & 15) * 16;
#pragma unroll
    for (int j = 0; j < 16; ++j)
      byv[j] = isf32 ? ((const float*)a.by2)[cb + j]
                     : bf2f(((const u16*)a.by2)[cb + j]);
  }

#pragma unroll
  for (int pass = 0; pass < 4; ++pass) {
    const int k = pass * 64 + (t >> 2), nc = (t & 3) * 16;
    u16 v[16];
    load16_bf(v, a.nY, ((size_t)m * LIB + k) * LIB + n0 + nc, isf32);
#pragma unroll
    for (int j = 0; j < 16; ++j) Bts[(nc + j) * TSTR + k] = v[j];
  }

  // build row list for class m within this block's b-half: per-wave chunk
  // reservation, no barriers in the scan loop (intra-list order irrelevant)
  __syncthreads();            // lcnt=0 visible
  const int bstart = half * (BATCH / 2), bend = bstart + BATCH / 2;
  for (int base = bstart; base < bend; base += 256) {
    const int b = base + t;
    const int e = a.opt[(size_t)b * os];
    unsigned long long mk = __ballot(e == m);
    const int nw = __popcll(mk);
    int wbase = 0;
    if (lane == 0 && nw) wbase = atomicAdd(&lcnt, nw);
    wbase = __shfl(wbase, 0);
    const int mypre = __popcll(mk & ((1ull << lane) - 1ull));
    if (e == m) list[wbase + mypre] = (u16)b;
  }
  __syncthreads();
  const int cnt = lcnt;
  const size_t out_off = (size_t)BATCH * LIB;

  for (int ch = 0; ch < cnt; ch += 16) {
    __syncthreads();
    {
      const int r = t >> 4, cb = (t & 15) * 16;
      if (ch + r < cnt) {
        const int row = list[ch + r];
        const float4* s0 = (const float4*)(py0 + (size_t)row * LIB + cb);
        const float4* s1 = (const float4*)(py1 + (size_t)row * LIB + cb);
        u16 o[16];
#pragma unroll
        for (int q = 0; q < 4; ++q) {
          float4 x0 = s0[q], x1 = s1[q];
          o[q * 4 + 0] = f2bf(x0.x + x1.x + byv[q * 4 + 0]);
          o[q * 4 + 1] = f2bf(x0.y + x1.y + byv[q * 4 + 1]);
          o[q * 4 + 2] = f2bf(x0.z + x1.z + byv[q * 4 + 2]);
          o[q * 4 + 3] = f2bf(x0.w + x1.w + byv[q * 4 + 3]);
        }
        *(uint4*)&Asm[r * TSTR + cb]     = *(const uint4*)&o[0];
        *(uint4*)&Asm[r * TSTR + cb + 8] = *(const uint4*)&o[8];
      } else {
        uint4 z{0, 0, 0, 0};
        *(uint4*)&Asm[r * TSTR + cb]     = z;
        *(uint4*)&Asm[r * TSTR + cb + 8] = z;
      }
    }
    __syncthreads();
    f32x4 acc = {};
#pragma unroll
    for (int kk = 0; kk < LIB; kk += 32) {
      bf16x8 av = *(const bf16x8*)&Asm[lr * TSTR + kk + lq * 8];
      bf16x8 bv = *(const bf16x8*)&Bts[(w * 16 + lr) * TSTR + kk + lq * 8];
      acc = __builtin_amdgcn_mfma_f32_16x16x32_bf16(av, bv, acc, 0, 0, 0);
    }
#pragma unroll
    for (int r = 0; r < 4; ++r) {
      const int rowc = lq * 4 + r;
      if (ch + rowc < cnt) {
        const size_t oi = out_off + (size_t)list[ch + rowc] * LIB
                        + (n0 + w * 16 + lr);
        if (of32) ((float*)a.out)[oi] = acc[r];
        else      ((u16*)a.out)[oi] = f2bf(acc[r]);
      }
    }
  }
}

extern "C" void kernel_launch(void* const* d_in, const int* in_sizes, int n_in,
                              void* d_out, int out_size, void* d_ws, size_t ws_size,
                              hipStream_t stream) {
  char* p = (char*)d_ws;
  auto alloc = [&](size_t bytes) { char* r = p; p += (bytes + 255) & ~(size_t)255; return r; };
  u16* all_state = (u16*)alloc((size_t)BATCH * DIN * 2);
  u16* h_x   = (u16*)alloc((size_t)BATCH * HID * 2);
  u16* h_y   = (u16*)alloc((size_t)BATCH * HID * 2);
  u16* WT1x  = (u16*)alloc((size_t)HID * DIN * 2);
  u16* WT1y  = (u16*)alloc((size_t)HID * DIN * 2);
  u16* WT2y  = (u16*)alloc((size_t)LIB * HID * 2);
  u16* T     = (u16*)alloc((size_t)LIB * HID * 2);   // (Wx2@nX)^T, bt layout
  float* b2x = (float*)alloc((size_t)LIB * 4);       // nX^T @ bx2, f32
  float* part = (float*)alloc((size_t)4 * BATCH * LIB * 4);   // split-K partials

  const void* state = d_in[0];
  const void* opt   = d_in[1];

  // 1) prep: concat + WT1x/WT1y only (864 pure-copy blocks, 9.2 KB LDS)
  PrepArgs pa;
  pa.state = state; pa.opt = (const int*)opt; pa.emb = d_in[2];
  pa.Wx1 = d_in[3]; pa.Wy1 = d_in[7];
  pa.all_state = all_state; pa.WT1x = WT1x; pa.WT1y = WT1y;
  prep_k<<<PREP_BLOCKS, 256, 0, stream>>>(pa);

  // 2) layer 1 (relu): 128x64, BK=96, 4/CU + WT2y/T/b' backfill (1156 blocks)
  G1Args g1;
  g1.all_state = all_state; g1.WT1x = WT1x; g1.WT1y = WT1y;
  g1.bx1 = d_in[4]; g1.by1 = d_in[8];
  g1.Wy2 = d_in[9]; g1.nX = d_in[11]; g1.Wx2 = d_in[5]; g1.bx2 = d_in[6];
  g1.state = state; g1.opt = opt;
  g1.h_x = h_x; g1.h_y = h_y; g1.WT2y = WT2y; g1.T = T; g1.b2x = b2x;
  gemm1_k<<<G1_BLOCKS, 256, 0, stream>>>(g1);

  // 3) layer-2 split-K x2 -> f32 partials (1024 blocks = 4/CU, 16 waves/CU)
  G2Args g2;
  g2.h_x = h_x; g2.h_y = h_y; g2.T = T; g2.WT2y = WT2y;
  g2.part = part; g2.state = state; g2.opt = opt;
  gemm2_k<<<dim3(LIB / 64, BATCH / 64, 4), 256, 0, stream>>>(g2);

  // 4) tail: routed gatherY (with y-combine) + out0 combine (768 blocks = 3/CU)
  TailArgs ta;
  ta.part = part; ta.nY = d_in[12]; ta.state = state; ta.by2 = d_in[10];
  ta.b2x = b2x; ta.opt = (const int*)opt; ta.out = d_out;
  tail_k<<<768, 256, 0, stream>>>(ta);
}